// Round 12
// baseline (102.869 us; speedup 1.0000x reference)
//
#include <hip/hip_runtime.h>
#include <hip/hip_bf16.h>

// Problem constants: B=4, N=2048, M=4096, D=1, C=4, K=32
#define B_   4
#define N_   2048
#define M_   4096
#define C_   4
#define K_   32
#define CK_  128
#define M32_ 128         // M/32

typedef float f32x4 __attribute__((ext_vector_type(4)));
typedef short s16x8 __attribute__((ext_vector_type(8)));

__device__ __forceinline__ short f2bf(float f) {
    union { __hip_bfloat16 h; short s; } u;
    u.h = __float2bfloat16(f);
    return u.s;
}

// ---------------- Stage 0a: z -> MFMA-fragment-ordered bf16 blocks, + xz copy ----------------
__global__ __launch_bounds__(256) void z2frag_kernel(
    const float* __restrict__ z, unsigned short* __restrict__ zf,
    const float* __restrict__ xz, float* __restrict__ out)
{
    const unsigned u = blockIdx.x * 256 + threadIdx.x;   // slot id, dest = u*8
    const int s   = u & 63;
    const int lg  = s >> 4, l15 = s & 15;
    const int m32 = (u >> 6) & (M32_ - 1);
    const int g   = (u >> 13) & 7;
    const int b   = u >> 16;
    const int c   = g >> 1;
    const int k   = (g & 1) * 16 + l15;
    const int m0  = m32 * 32 + lg * 8;

    const float* src = &z[(((size_t)(b * C_ + c)) * M_ + m0) * K_ + k];
    s16x8 pk;
    #pragma unroll
    for (int e = 0; e < 8; ++e) pk[e] = f2bf(src[(size_t)e * K_]);
    *(s16x8*)&zf[(size_t)u * 8] = pk;

    if (u < 1024) *(f32x4*)&out[u * 4] = *(const f32x4*)&xz[u * 4];  // xz passthrough
}

// ---------------- Stage 1 (MFMA): zt = full-M GEMM, no partials, no reduce ----------------
// Tile 64n x 64ck, grid (32 nblk, 2 ckhalf, 4 b) = 256 blocks (1/CU), 512 thr =
// 8 waves (4 wq x 16n, 2 wc x 32ck). K-loop = 128 frag-steps over M=4096 with
// depth-2 register prefetch from L2-resident zf. Writes bf16 zt directly.
__global__ __launch_bounds__(512, 4) void zt_mfma_kernel(
    const float* __restrict__ xz, const float* __restrict__ x,
    const unsigned short* __restrict__ zf, const float* __restrict__ ls,
    unsigned short* __restrict__ ztb)
{
    __shared__ __align__(16) float xz_s[M_];   // 16 KB

    const int tid  = threadIdx.x;
    const int lane = tid & 63;
    const int w    = tid >> 6;
    const int wq   = w >> 1;             // n quadrant (16 rows)
    const int wc   = w & 1;              // ck half (32 of this block's 64)
    const int l15  = lane & 15;
    const int lg   = lane >> 4;
    const int nblk = blockIdx.x * 64;
    const int ckh  = blockIdx.y;
    const int b    = blockIdx.z;

    // w = exp(coef*d^2) = exp2(coef2*d^2)
    const float coef2 = -0.5f * __expf(-ls[0]) * 1.4426950408889634f;

    const float xv = x[b * N_ + nblk + wq * 16 + l15];

    for (int i = tid; i < M_; i += 512) xz_s[i] = xz[i];
    __syncthreads();

    f32x4 acc[2];
    acc[0] = (f32x4)0.0f; acc[1] = (f32x4)0.0f;

    // frag (fc, ms32) at fbase + (fc*M32_ + ms32)*512
    const unsigned short* fbase =
        &zf[((size_t)(b * 8 + ckh * 4 + wc * 2)) * M32_ * 512 + lane * 8];

    s16x8 p0[2], p1[2];
    #pragma unroll
    for (int fc = 0; fc < 2; ++fc) {
        p0[fc] = *(const s16x8*)&fbase[(size_t)fc * M32_ * 512];
        p1[fc] = *(const s16x8*)&fbase[((size_t)fc * M32_ + 1) * 512];
    }

    #pragma unroll 4
    for (int ms32 = 0; ms32 < M32_; ++ms32) {
        s16x8 cb[2];
        cb[0] = p0[0]; cb[1] = p0[1];
        p0[0] = p1[0]; p0[1] = p1[1];
        if (ms32 + 2 < M32_) {
            #pragma unroll
            for (int fc = 0; fc < 2; ++fc)
                p1[fc] = *(const s16x8*)&fbase[((size_t)fc * M32_ + ms32 + 2) * 512];
        }
        const float* xzp = &xz_s[ms32 * 32 + lg * 8];
        const f32x4 t0 = *reinterpret_cast<const f32x4*>(xzp);
        const f32x4 t1 = *reinterpret_cast<const f32x4*>(xzp + 4);
        const float tt[8] = {t0.x, t0.y, t0.z, t0.w, t1.x, t1.y, t1.z, t1.w};
        s16x8 af;
        #pragma unroll
        for (int j = 0; j < 8; ++j) {
            const float d = tt[j] - xv;
            af[j] = f2bf(exp2f(coef2 * d * d));
        }
        #pragma unroll
        for (int fc = 0; fc < 2; ++fc)
            acc[fc] = __builtin_amdgcn_mfma_f32_16x16x32_bf16(af, cb[fc], acc[fc], 0, 0, 0);
    }

    // write bf16 zt; D layout: col(=ck)=lane&15, row(=n)=(lane>>4)*4+r
    #pragma unroll
    for (int fc = 0; fc < 2; ++fc) {
        const int ck = ckh * 64 + wc * 32 + fc * 16 + l15;
        const int c  = ck >> 5, k = ck & 31;
        const int n0 = nblk + wq * 16 + lg * 4;
        #pragma unroll
        for (int r = 0; r < 4; ++r)
            ztb[(((size_t)b * C_ + c) * N_ + n0 + r) * K_ + k] =
                (unsigned short)f2bf(acc[fc][r]);
    }
}

// ---------------- Stage 2 (MFMA, symmetric): out = zt @ zt^T per (b,c) ----------------
// R9 configuration exactly (measured best): upper-tri pairs tile-fastest,
// t_s + t2 LDS, all-f32x4 stores.
__global__ __launch_bounds__(256, 2) void out_mfma_sym_kernel(
    const unsigned short* __restrict__ ztb, float* __restrict__ out)
{
    __shared__ __align__(16) float t_s[64][132];   // 33.8 KB: n-half rows x 128 m
    __shared__ __align__(16) float t2 [128][68];   // 34.8 KB: 128 m x n-half cols

    const int tid  = threadIdx.x;
    const int lane = tid & 63;
    const int wave = tid >> 6;
    const int wn   = wave >> 1;       // n 64-half
    const int wm   = wave & 1;        // m 64-half
    const int l15  = lane & 15;
    const int lg   = lane >> 4;

    // decode upper-tri pair: xid = tj*(tj+1)/2 + ti, ti <= tj
    const int xid = blockIdx.x;
    int tj = (int)((sqrtf(8.f * xid + 1.f) - 1.f) * 0.5f);
    while (tj * (tj + 1) / 2 > xid) --tj;
    while ((tj + 1) * (tj + 2) / 2 <= xid) ++tj;
    const int ti   = xid - tj * (tj + 1) / 2;
    const int nblk = ti * 128;
    const int mblk = tj * 128;
    const int bc   = blockIdx.y;

    const unsigned short* base = ztb + (size_t)bc * (N_ * K_);

    s16x8 afr[4], bfr[4];
    #pragma unroll
    for (int f = 0; f < 4; ++f) {
        const int n = nblk + wn * 64 + f * 16 + l15;
        afr[f] = *reinterpret_cast<const s16x8*>(&base[(size_t)n * K_ + lg * 8]);
        const int m = mblk + wm * 64 + f * 16 + l15;
        bfr[f] = *reinterpret_cast<const s16x8*>(&base[(size_t)m * K_ + lg * 8]);
    }

    f32x4 acc[4][4];
    #pragma unroll
    for (int i = 0; i < 4; ++i)
        #pragma unroll
        for (int j = 0; j < 4; ++j) acc[i][j] = (f32x4)0.0f;

    #pragma unroll
    for (int fa = 0; fa < 4; ++fa)
        #pragma unroll
        for (int fm = 0; fm < 4; ++fm)
            acc[fa][fm] = __builtin_amdgcn_mfma_f32_16x16x32_bf16(
                afr[fa], bfr[fm], acc[fa][fm], 0, 0, 0);

    float* ob = out + (size_t)bc * N_ * N_;
    const bool offdiag = (ti != tj);

    #pragma unroll
    for (int p = 0; p < 2; ++p) {     // n-halves
        if (p) __syncthreads();       // t_s/t2 free (pass-0 readers done)
        if (wn == p) {
            #pragma unroll
            for (int fa = 0; fa < 4; ++fa) {
                const int row0 = fa * 16 + lg * 4;          // n within half
                #pragma unroll
                for (int fm = 0; fm < 4; ++fm) {
                    const int mcol = wm * 64 + fm * 16 + l15;
                    #pragma unroll
                    for (int r = 0; r < 4; ++r)
                        t_s[row0 + r][mcol] = acc[fa][fm][r];
                    *(f32x4*)&t2[mcol][row0] = acc[fa][fm];  // vector: n-column at fixed m
                }
            }
        }
        __syncthreads();
        // direct: rows n (64), cols m (128)
        #pragma unroll
        for (int it = 0; it < 8; ++it) {
            const int e   = tid + it * 256;
            const int row = e >> 5;
            const int c4  = e & 31;
            const f32x4 v = *reinterpret_cast<const f32x4*>(&t_s[row][c4 * 4]);
            *(f32x4*)&ob[(size_t)(nblk + p * 64 + row) * N_ + mblk + c4 * 4] = v;
        }
        // mirror: rows m (128), cols n (64) — skip on diagonal tiles
        if (offdiag) {
            #pragma unroll
            for (int it = 0; it < 8; ++it) {
                const int e    = tid + it * 256;
                const int mrow = e >> 4;
                const int nc4  = e & 15;
                const f32x4 v  = *reinterpret_cast<const f32x4*>(&t2[mrow][nc4 * 4]);
                *(f32x4*)&ob[(size_t)(mblk + mrow) * N_ + nblk + p * 64 + nc4 * 4] = v;
            }
        }
    }
}

extern "C" void kernel_launch(void* const* d_in, const int* in_sizes, int n_in,
                              void* d_out, int out_size, void* d_ws, size_t ws_size,
                              hipStream_t stream)
{
    const float* xz = (const float*)d_in[0];
    const float* x  = (const float*)d_in[1];
    const float* z  = (const float*)d_in[2];
    const float* ls = (const float*)d_in[3];
    float* out = (float*)d_out;

    (void)in_sizes; (void)n_in; (void)out_size; (void)ws_size;

    const size_t ztf = (size_t)B_ * C_ * N_ * K_;            // 1 Mi elements
    unsigned short* ztb = (unsigned short*)d_ws;             // bf16 zt: 2 MiB
    unsigned short* zf  = ztb + ztf;                         // frag-ordered bf16 z: 4 MiB

    // z -> frag-ordered bf16, + xz passthrough
    z2frag_kernel<<<dim3((unsigned)(B_ * 8 * M32_ * 64 / 256)), dim3(256), 0, stream>>>(
        z, zf, xz, out);

    // zt: 256 blocks (1/CU), full-M K-loop, direct bf16 output
    zt_mfma_kernel<<<dim3(N_ / 64, 2, B_), dim3(512), 0, stream>>>(xz, x, zf, ls, ztb);

    // 136 upper-tri tile pairs x 16 (b,c) — tile-fastest (R9 order)
    out_mfma_sym_kernel<<<dim3(136, B_ * C_), dim3(256), 0, stream>>>(ztb, out + M_);
}

// Round 13
// 85.714 us; speedup vs baseline: 1.2001x; 1.2001x over previous
//
#include <hip/hip_runtime.h>
#include <hip/hip_bf16.h>

// Problem constants: B=4, N=2048, M=4096, D=1, C=4, K=32
#define B_   4
#define N_   2048
#define M_   4096
#define C_   4
#define K_   32
#define CK_  128
#define M32_ 128         // M/32

typedef float f32x4 __attribute__((ext_vector_type(4)));
typedef short s16x8 __attribute__((ext_vector_type(8)));

__device__ __forceinline__ short f2bf(float f) {
    union { __hip_bfloat16 h; short s; } u;
    u.h = __float2bfloat16(f);
    return u.s;
}
__device__ __forceinline__ float bf2f(unsigned short u) {
    return __uint_as_float((unsigned)u << 16);
}

// ---------------- Stage 0a: z -> MFMA-fragment-ordered bf16 blocks, + xz copy ----------------
__global__ __launch_bounds__(256) void z2frag_kernel(
    const float* __restrict__ z, unsigned short* __restrict__ zf,
    const float* __restrict__ xz, float* __restrict__ out)
{
    const unsigned u = blockIdx.x * 256 + threadIdx.x;   // slot id, dest = u*8
    const int s   = u & 63;
    const int lg  = s >> 4, l15 = s & 15;
    const int m32 = (u >> 6) & (M32_ - 1);
    const int g   = (u >> 13) & 7;
    const int b   = u >> 16;
    const int c   = g >> 1;
    const int k   = (g & 1) * 16 + l15;
    const int m0  = m32 * 32 + lg * 8;

    const float* src = &z[(((size_t)(b * C_ + c)) * M_ + m0) * K_ + k];
    s16x8 pk;
    #pragma unroll
    for (int e = 0; e < 8; ++e) pk[e] = f2bf(src[(size_t)e * K_]);
    *(s16x8*)&zf[(size_t)u * 8] = pk;

    if (u < 1024) *(f32x4*)&out[u * 4] = *(const f32x4*)&xz[u * 4];  // xz passthrough
}

// ---------------- Stage 1 (MFMA): zt partials, no z-LDS, no main-loop barriers ----
template <int MS>
__global__ __launch_bounds__(512, 4) void zt_mfma_kernel(
    const float* __restrict__ xz, const float* __restrict__ x,
    const unsigned short* __restrict__ zf, const float* __restrict__ ls,
    unsigned short* __restrict__ ztp)
{
    constexpr int MCH = M_ / MS;         // 512 for MS=8
    constexpr int L   = MCH / 32;        // 16 frag-steps
    __shared__ __align__(16) float xz_s[MCH];

    const int tid  = threadIdx.x;
    const int lane = tid & 63;
    const int w    = tid >> 6;
    const int wq   = w >> 1;             // n quadrant (32 rows)
    const int wc   = w & 1;              // ck half
    const int l15  = lane & 15;
    const int lg   = lane >> 4;
    const int ms   = blockIdx.x;
    const int nblk = blockIdx.y * 128;
    const int b    = blockIdx.z;

    // w = exp(coef*d^2) = exp2(coef2*d^2); v_exp_f32 IS 2^x -> saves the log2e mul
    const float coef2 = -0.5f * __expf(-ls[0]) * 1.4426950408889634f;

    float xv[2];
    #pragma unroll
    for (int fa = 0; fa < 2; ++fa)
        xv[fa] = x[b * N_ + nblk + wq * 32 + fa * 16 + l15];

    const int mstart = ms * MCH;
    for (int i = tid; i < MCH; i += 512) xz_s[i] = xz[mstart + i];
    __syncthreads();

    f32x4 acc[2][4];
    #pragma unroll
    for (int i = 0; i < 2; ++i)
        #pragma unroll
        for (int j = 0; j < 4; ++j) acc[i][j] = (f32x4)0.0f;

    const unsigned short* fbase =
        &zf[(((size_t)(b * 8 + wc * 4)) * M32_ + mstart / 32) * 512 + lane * 8];

    s16x8 nb[4];
    #pragma unroll
    for (int fc = 0; fc < 4; ++fc)
        nb[fc] = *(const s16x8*)&fbase[(size_t)fc * M32_ * 512];

    #pragma unroll 4
    for (int ms32 = 0; ms32 < L; ++ms32) {
        s16x8 cb[4];
        #pragma unroll
        for (int fc = 0; fc < 4; ++fc) cb[fc] = nb[fc];
        if (ms32 + 1 < L) {
            #pragma unroll
            for (int fc = 0; fc < 4; ++fc)
                nb[fc] = *(const s16x8*)&fbase[((size_t)fc * M32_ + ms32 + 1) * 512];
        }
        const float* xzp = &xz_s[ms32 * 32 + lg * 8];
        const f32x4 t0 = *reinterpret_cast<const f32x4*>(xzp);
        const f32x4 t1 = *reinterpret_cast<const f32x4*>(xzp + 4);
        const float tt[8] = {t0.x, t0.y, t0.z, t0.w, t1.x, t1.y, t1.z, t1.w};
        s16x8 af[2];
        #pragma unroll
        for (int fa = 0; fa < 2; ++fa) {
            #pragma unroll
            for (int j = 0; j < 8; ++j) {
                const float d = tt[j] - xv[fa];
                af[fa][j] = f2bf(exp2f(coef2 * d * d));
            }
        }
        #pragma unroll
        for (int fa = 0; fa < 2; ++fa)
            #pragma unroll
            for (int fc = 0; fc < 4; ++fc)
                acc[fa][fc] = __builtin_amdgcn_mfma_f32_16x16x32_bf16(
                    af[fa], cb[fc], acc[fa][fc], 0, 0, 0);
    }

    unsigned short* dst = ztp + (size_t)ms * (B_ * C_ * N_ * K_);
    #pragma unroll
    for (int fc = 0; fc < 4; ++fc) {
        const int ck = wc * 64 + fc * 16 + l15;
        const int c  = ck >> 5, k = ck & 31;
        #pragma unroll
        for (int fa = 0; fa < 2; ++fa) {
            const int n0 = nblk + wq * 32 + fa * 16 + lg * 4;
            #pragma unroll
            for (int r = 0; r < 4; ++r)
                dst[(((size_t)b * C_ + c) * N_ + n0 + r) * K_ + k] =
                    (unsigned short)f2bf(acc[fa][fc][r]);
        }
    }
}

// ---------------- Stage 1b: reduce MS bf16 partials -> bf16 zt ----------------
template <int MS>
__global__ __launch_bounds__(256) void zt_reduce_kernel(
    const unsigned short* __restrict__ ztp, unsigned short* __restrict__ ztb)
{
    const size_t t      = (size_t)blockIdx.x * 256 + threadIdx.x;
    const size_t stride = (size_t)(B_ * C_ * N_ * K_);
    float s0 = 0.f, s1 = 0.f, s2 = 0.f, s3 = 0.f;
    #pragma unroll
    for (int p = 0; p < MS; ++p) {
        const ushort4 v = *(const ushort4*)&ztp[(size_t)p * stride + t * 4];
        s0 += bf2f(v.x); s1 += bf2f(v.y); s2 += bf2f(v.z); s3 += bf2f(v.w);
    }
    ushort4 pk;
    pk.x = (unsigned short)f2bf(s0); pk.y = (unsigned short)f2bf(s1);
    pk.z = (unsigned short)f2bf(s2); pk.w = (unsigned short)f2bf(s3);
    *(ushort4*)&ztb[t * 4] = pk;
}

// ---------------- Stage 2 (MFMA, symmetric): out = zt @ zt^T per (b,c) ----------------
// R9 configuration exactly: upper-tri pairs TILE-FASTEST, t_s + t2 LDS, all-f32x4 stores.
__global__ __launch_bounds__(256, 2) void out_mfma_sym_kernel(
    const unsigned short* __restrict__ ztb, float* __restrict__ out)
{
    __shared__ __align__(16) float t_s[64][132];   // 33.8 KB: n-half rows x 128 m
    __shared__ __align__(16) float t2 [128][68];   // 34.8 KB: 128 m x n-half cols

    const int tid  = threadIdx.x;
    const int lane = tid & 63;
    const int wave = tid >> 6;
    const int wn   = wave >> 1;       // n 64-half
    const int wm   = wave & 1;        // m 64-half
    const int l15  = lane & 15;
    const int lg   = lane >> 4;

    // decode upper-tri pair: xid = tj*(tj+1)/2 + ti, ti <= tj
    const int xid = blockIdx.x;
    int tj = (int)((sqrtf(8.f * xid + 1.f) - 1.f) * 0.5f);
    while (tj * (tj + 1) / 2 > xid) --tj;
    while ((tj + 1) * (tj + 2) / 2 <= xid) ++tj;
    const int ti   = xid - tj * (tj + 1) / 2;
    const int nblk = ti * 128;
    const int mblk = tj * 128;
    const int bc   = blockIdx.y;

    const unsigned short* base = ztb + (size_t)bc * (N_ * K_);

    s16x8 afr[4], bfr[4];
    #pragma unroll
    for (int f = 0; f < 4; ++f) {
        const int n = nblk + wn * 64 + f * 16 + l15;
        afr[f] = *reinterpret_cast<const s16x8*>(&base[(size_t)n * K_ + lg * 8]);
        const int m = mblk + wm * 64 + f * 16 + l15;
        bfr[f] = *reinterpret_cast<const s16x8*>(&base[(size_t)m * K_ + lg * 8]);
    }

    f32x4 acc[4][4];
    #pragma unroll
    for (int i = 0; i < 4; ++i)
        #pragma unroll
        for (int j = 0; j < 4; ++j) acc[i][j] = (f32x4)0.0f;

    #pragma unroll
    for (int fa = 0; fa < 4; ++fa)
        #pragma unroll
        for (int fm = 0; fm < 4; ++fm)
            acc[fa][fm] = __builtin_amdgcn_mfma_f32_16x16x32_bf16(
                afr[fa], bfr[fm], acc[fa][fm], 0, 0, 0);

    float* ob = out + (size_t)bc * N_ * N_;
    const bool offdiag = (ti != tj);

    #pragma unroll
    for (int p = 0; p < 2; ++p) {     // n-halves
        if (p) __syncthreads();       // t_s/t2 free (pass-0 readers done)
        if (wn == p) {
            #pragma unroll
            for (int fa = 0; fa < 4; ++fa) {
                const int row0 = fa * 16 + lg * 4;          // n within half
                #pragma unroll
                for (int fm = 0; fm < 4; ++fm) {
                    const int mcol = wm * 64 + fm * 16 + l15;
                    #pragma unroll
                    for (int r = 0; r < 4; ++r)
                        t_s[row0 + r][mcol] = acc[fa][fm][r];
                    *(f32x4*)&t2[mcol][row0] = acc[fa][fm];  // vector: n-column at fixed m
                }
            }
        }
        __syncthreads();
        // direct: rows n (64), cols m (128)
        #pragma unroll
        for (int it = 0; it < 8; ++it) {
            const int e   = tid + it * 256;
            const int row = e >> 5;
            const int c4  = e & 31;
            const f32x4 v = *reinterpret_cast<const f32x4*>(&t_s[row][c4 * 4]);
            *(f32x4*)&ob[(size_t)(nblk + p * 64 + row) * N_ + mblk + c4 * 4] = v;
        }
        // mirror: rows m (128), cols n (64) — skip on diagonal tiles
        if (offdiag) {
            #pragma unroll
            for (int it = 0; it < 8; ++it) {
                const int e    = tid + it * 256;
                const int mrow = e >> 4;
                const int nc4  = e & 15;
                const f32x4 v  = *reinterpret_cast<const f32x4*>(&t2[mrow][nc4 * 4]);
                *(f32x4*)&ob[(size_t)(mblk + mrow) * N_ + nblk + p * 64 + nc4 * 4] = v;
            }
        }
    }
}

extern "C" void kernel_launch(void* const* d_in, const int* in_sizes, int n_in,
                              void* d_out, int out_size, void* d_ws, size_t ws_size,
                              hipStream_t stream)
{
    const float* xz = (const float*)d_in[0];
    const float* x  = (const float*)d_in[1];
    const float* z  = (const float*)d_in[2];
    const float* ls = (const float*)d_in[3];
    float* out = (float*)d_out;

    (void)in_sizes; (void)n_in; (void)out_size;

    const size_t ztf = (size_t)B_ * C_ * N_ * K_;            // 1 Mi elements
    unsigned short* ztb = (unsigned short*)d_ws;             // final bf16 zt: 2 MiB
    unsigned short* zf  = ztb + ztf;                         // frag-ordered bf16 z: 4 MiB
    unsigned short* ztp = zf + (size_t)B_ * CK_ * M_;        // bf16 partials

    // z -> frag-ordered bf16, + xz passthrough
    z2frag_kernel<<<dim3((unsigned)(B_ * 8 * M32_ * 64 / 256)), dim3(256), 0, stream>>>(
        z, zf, xz, out);

    const size_t base_b = ztf * 2 + (size_t)B_ * CK_ * M_ * 2;   // 6 MiB
    if (ws_size >= base_b + (size_t)8 * ztf * 2) {
        zt_mfma_kernel<8><<<dim3(8, N_ / 128, B_), dim3(512), 0, stream>>>(xz, x, zf, ls, ztp);
        zt_reduce_kernel<8><<<dim3(1024), dim3(256), 0, stream>>>(ztp, ztb);
    } else if (ws_size >= base_b + (size_t)4 * ztf * 2) {
        zt_mfma_kernel<4><<<dim3(4, N_ / 128, B_), dim3(512), 0, stream>>>(xz, x, zf, ls, ztp);
        zt_reduce_kernel<4><<<dim3(1024), dim3(256), 0, stream>>>(ztp, ztb);
    } else {
        zt_mfma_kernel<2><<<dim3(2, N_ / 128, B_), dim3(512), 0, stream>>>(xz, x, zf, ls, ztp);
        zt_reduce_kernel<2><<<dim3(1024), dim3(256), 0, stream>>>(ztp, ztb);
    }

    // 136 upper-tri tile pairs x 16 (b,c) — TILE-FASTEST (R9's measured-best order)
    out_mfma_sym_kernel<<<dim3(136, B_ * C_), dim3(256), 0, stream>>>(ztb, out + M_);
}

// Round 14
// 78.927 us; speedup vs baseline: 1.3033x; 1.0860x over previous
//
#include <hip/hip_runtime.h>
#include <hip/hip_bf16.h>

// Problem constants: B=4, N=2048, M=4096, D=1, C=4, K=32
#define B_   4
#define N_   2048
#define M_   4096
#define C_   4
#define K_   32
#define CK_  128
#define M32_ 128         // M/32

typedef float f32x4 __attribute__((ext_vector_type(4)));
typedef short s16x8 __attribute__((ext_vector_type(8)));

__device__ __forceinline__ short f2bf(float f) {
    union { __hip_bfloat16 h; short s; } u;
    u.h = __float2bfloat16(f);
    return u.s;
}
__device__ __forceinline__ float bf2f(unsigned short u) {
    return __uint_as_float((unsigned)u << 16);
}

// ---------------- Stage 0a: z -> MFMA-fragment-ordered bf16 blocks, + xz copy ----------------
__global__ __launch_bounds__(256) void z2frag_kernel(
    const float* __restrict__ z, unsigned short* __restrict__ zf,
    const float* __restrict__ xz, float* __restrict__ out)
{
    const unsigned u = blockIdx.x * 256 + threadIdx.x;   // slot id, dest = u*8
    const int s   = u & 63;
    const int lg  = s >> 4, l15 = s & 15;
    const int m32 = (u >> 6) & (M32_ - 1);
    const int g   = (u >> 13) & 7;
    const int b   = u >> 16;
    const int c   = g >> 1;
    const int k   = (g & 1) * 16 + l15;
    const int m0  = m32 * 32 + lg * 8;

    const float* src = &z[(((size_t)(b * C_ + c)) * M_ + m0) * K_ + k];
    s16x8 pk;
    #pragma unroll
    for (int e = 0; e < 8; ++e) pk[e] = f2bf(src[(size_t)e * K_]);
    *(s16x8*)&zf[(size_t)u * 8] = pk;

    if (u < 1024) *(f32x4*)&out[u * 4] = *(const f32x4*)&xz[u * 4];  // xz passthrough
}

// ---------------- Stage 1 (MFMA): zt partials, no z-LDS, no main-loop barriers ----
template <int MS>
__global__ __launch_bounds__(512, 4) void zt_mfma_kernel(
    const float* __restrict__ xz, const float* __restrict__ x,
    const unsigned short* __restrict__ zf, const float* __restrict__ ls,
    unsigned short* __restrict__ ztp)
{
    constexpr int MCH = M_ / MS;         // 512 for MS=8
    constexpr int L   = MCH / 32;        // 16 frag-steps
    __shared__ __align__(16) float xz_s[MCH];

    const int tid  = threadIdx.x;
    const int lane = tid & 63;
    const int w    = tid >> 6;
    const int wq   = w >> 1;             // n quadrant (32 rows)
    const int wc   = w & 1;              // ck half
    const int l15  = lane & 15;
    const int lg   = lane >> 4;
    const int ms   = blockIdx.x;
    const int nblk = blockIdx.y * 128;
    const int b    = blockIdx.z;

    // __expf = native v_exp path (R9 known-good). exp2f regressed (precise OCML).
    const float coef = -0.5f * __expf(-ls[0]);

    float xv[2];
    #pragma unroll
    for (int fa = 0; fa < 2; ++fa)
        xv[fa] = x[b * N_ + nblk + wq * 32 + fa * 16 + l15];

    const int mstart = ms * MCH;
    for (int i = tid; i < MCH; i += 512) xz_s[i] = xz[mstart + i];
    __syncthreads();

    f32x4 acc[2][4];
    #pragma unroll
    for (int i = 0; i < 2; ++i)
        #pragma unroll
        for (int j = 0; j < 4; ++j) acc[i][j] = (f32x4)0.0f;

    const unsigned short* fbase =
        &zf[(((size_t)(b * 8 + wc * 4)) * M32_ + mstart / 32) * 512 + lane * 8];

    s16x8 nb[4];
    #pragma unroll
    for (int fc = 0; fc < 4; ++fc)
        nb[fc] = *(const s16x8*)&fbase[(size_t)fc * M32_ * 512];

    #pragma unroll 4
    for (int ms32 = 0; ms32 < L; ++ms32) {
        s16x8 cb[4];
        #pragma unroll
        for (int fc = 0; fc < 4; ++fc) cb[fc] = nb[fc];
        if (ms32 + 1 < L) {
            #pragma unroll
            for (int fc = 0; fc < 4; ++fc)
                nb[fc] = *(const s16x8*)&fbase[((size_t)fc * M32_ + ms32 + 1) * 512];
        }
        const float* xzp = &xz_s[ms32 * 32 + lg * 8];
        const f32x4 t0 = *reinterpret_cast<const f32x4*>(xzp);
        const f32x4 t1 = *reinterpret_cast<const f32x4*>(xzp + 4);
        const float tt[8] = {t0.x, t0.y, t0.z, t0.w, t1.x, t1.y, t1.z, t1.w};
        s16x8 af[2];
        #pragma unroll
        for (int fa = 0; fa < 2; ++fa) {
            #pragma unroll
            for (int j = 0; j < 8; ++j) {
                const float d = tt[j] - xv[fa];
                af[fa][j] = f2bf(__expf(coef * d * d));
            }
        }
        #pragma unroll
        for (int fa = 0; fa < 2; ++fa)
            #pragma unroll
            for (int fc = 0; fc < 4; ++fc)
                acc[fa][fc] = __builtin_amdgcn_mfma_f32_16x16x32_bf16(
                    af[fa], cb[fc], acc[fa][fc], 0, 0, 0);
    }

    unsigned short* dst = ztp + (size_t)ms * (B_ * C_ * N_ * K_);
    #pragma unroll
    for (int fc = 0; fc < 4; ++fc) {
        const int ck = wc * 64 + fc * 16 + l15;
        const int c  = ck >> 5, k = ck & 31;
        #pragma unroll
        for (int fa = 0; fa < 2; ++fa) {
            const int n0 = nblk + wq * 32 + fa * 16 + lg * 4;
            #pragma unroll
            for (int r = 0; r < 4; ++r)
                dst[(((size_t)b * C_ + c) * N_ + n0 + r) * K_ + k] =
                    (unsigned short)f2bf(acc[fa][fc][r]);
        }
    }
}

// ---------------- Stage 1b: reduce MS bf16 partials -> bf16 zt ----------------
template <int MS>
__global__ __launch_bounds__(256) void zt_reduce_kernel(
    const unsigned short* __restrict__ ztp, unsigned short* __restrict__ ztb)
{
    const size_t t      = (size_t)blockIdx.x * 256 + threadIdx.x;
    const size_t stride = (size_t)(B_ * C_ * N_ * K_);
    float s0 = 0.f, s1 = 0.f, s2 = 0.f, s3 = 0.f;
    #pragma unroll
    for (int p = 0; p < MS; ++p) {
        const ushort4 v = *(const ushort4*)&ztp[(size_t)p * stride + t * 4];
        s0 += bf2f(v.x); s1 += bf2f(v.y); s2 += bf2f(v.z); s3 += bf2f(v.w);
    }
    ushort4 pk;
    pk.x = (unsigned short)f2bf(s0); pk.y = (unsigned short)f2bf(s1);
    pk.z = (unsigned short)f2bf(s2); pk.w = (unsigned short)f2bf(s3);
    *(ushort4*)&ztb[t * 4] = pk;
}

// ---------------- Stage 2 (MFMA, symmetric): out = zt @ zt^T per (b,c) ----------------
// R9 configuration exactly: upper-tri pairs TILE-FASTEST, t_s + t2 LDS, all-f32x4 stores.
__global__ __launch_bounds__(256, 2) void out_mfma_sym_kernel(
    const unsigned short* __restrict__ ztb, float* __restrict__ out)
{
    __shared__ __align__(16) float t_s[64][132];   // 33.8 KB: n-half rows x 128 m
    __shared__ __align__(16) float t2 [128][68];   // 34.8 KB: 128 m x n-half cols

    const int tid  = threadIdx.x;
    const int lane = tid & 63;
    const int wave = tid >> 6;
    const int wn   = wave >> 1;       // n 64-half
    const int wm   = wave & 1;        // m 64-half
    const int l15  = lane & 15;
    const int lg   = lane >> 4;

    // decode upper-tri pair: xid = tj*(tj+1)/2 + ti, ti <= tj
    const int xid = blockIdx.x;
    int tj = (int)((sqrtf(8.f * xid + 1.f) - 1.f) * 0.5f);
    while (tj * (tj + 1) / 2 > xid) --tj;
    while ((tj + 1) * (tj + 2) / 2 <= xid) ++tj;
    const int ti   = xid - tj * (tj + 1) / 2;
    const int nblk = ti * 128;
    const int mblk = tj * 128;
    const int bc   = blockIdx.y;

    const unsigned short* base = ztb + (size_t)bc * (N_ * K_);

    s16x8 afr[4], bfr[4];
    #pragma unroll
    for (int f = 0; f < 4; ++f) {
        const int n = nblk + wn * 64 + f * 16 + l15;
        afr[f] = *reinterpret_cast<const s16x8*>(&base[(size_t)n * K_ + lg * 8]);
        const int m = mblk + wm * 64 + f * 16 + l15;
        bfr[f] = *reinterpret_cast<const s16x8*>(&base[(size_t)m * K_ + lg * 8]);
    }

    f32x4 acc[4][4];
    #pragma unroll
    for (int i = 0; i < 4; ++i)
        #pragma unroll
        for (int j = 0; j < 4; ++j) acc[i][j] = (f32x4)0.0f;

    #pragma unroll
    for (int fa = 0; fa < 4; ++fa)
        #pragma unroll
        for (int fm = 0; fm < 4; ++fm)
            acc[fa][fm] = __builtin_amdgcn_mfma_f32_16x16x32_bf16(
                afr[fa], bfr[fm], acc[fa][fm], 0, 0, 0);

    float* ob = out + (size_t)bc * N_ * N_;
    const bool offdiag = (ti != tj);

    #pragma unroll
    for (int p = 0; p < 2; ++p) {     // n-halves
        if (p) __syncthreads();       // t_s/t2 free (pass-0 readers done)
        if (wn == p) {
            #pragma unroll
            for (int fa = 0; fa < 4; ++fa) {
                const int row0 = fa * 16 + lg * 4;          // n within half
                #pragma unroll
                for (int fm = 0; fm < 4; ++fm) {
                    const int mcol = wm * 64 + fm * 16 + l15;
                    #pragma unroll
                    for (int r = 0; r < 4; ++r)
                        t_s[row0 + r][mcol] = acc[fa][fm][r];
                    *(f32x4*)&t2[mcol][row0] = acc[fa][fm];  // vector: n-column at fixed m
                }
            }
        }
        __syncthreads();
        // direct: rows n (64), cols m (128)
        #pragma unroll
        for (int it = 0; it < 8; ++it) {
            const int e   = tid + it * 256;
            const int row = e >> 5;
            const int c4  = e & 31;
            const f32x4 v = *reinterpret_cast<const f32x4*>(&t_s[row][c4 * 4]);
            *(f32x4*)&ob[(size_t)(nblk + p * 64 + row) * N_ + mblk + c4 * 4] = v;
        }
        // mirror: rows m (128), cols n (64) — skip on diagonal tiles
        if (offdiag) {
            #pragma unroll
            for (int it = 0; it < 8; ++it) {
                const int e    = tid + it * 256;
                const int mrow = e >> 4;
                const int nc4  = e & 15;
                const f32x4 v  = *reinterpret_cast<const f32x4*>(&t2[mrow][nc4 * 4]);
                *(f32x4*)&ob[(size_t)(mblk + mrow) * N_ + nblk + p * 64 + nc4 * 4] = v;
            }
        }
    }
}

extern "C" void kernel_launch(void* const* d_in, const int* in_sizes, int n_in,
                              void* d_out, int out_size, void* d_ws, size_t ws_size,
                              hipStream_t stream)
{
    const float* xz = (const float*)d_in[0];
    const float* x  = (const float*)d_in[1];
    const float* z  = (const float*)d_in[2];
    const float* ls = (const float*)d_in[3];
    float* out = (float*)d_out;

    (void)in_sizes; (void)n_in; (void)out_size;

    const size_t ztf = (size_t)B_ * C_ * N_ * K_;            // 1 Mi elements
    unsigned short* ztb = (unsigned short*)d_ws;             // final bf16 zt: 2 MiB
    unsigned short* zf  = ztb + ztf;                         // frag-ordered bf16 z: 4 MiB
    unsigned short* ztp = zf + (size_t)B_ * CK_ * M_;        // bf16 partials

    // z -> frag-ordered bf16, + xz passthrough
    z2frag_kernel<<<dim3((unsigned)(B_ * 8 * M32_ * 64 / 256)), dim3(256), 0, stream>>>(
        z, zf, xz, out);

    const size_t base_b = ztf * 2 + (size_t)B_ * CK_ * M_ * 2;   // 6 MiB
    if (ws_size >= base_b + (size_t)8 * ztf * 2) {
        zt_mfma_kernel<8><<<dim3(8, N_ / 128, B_), dim3(512), 0, stream>>>(xz, x, zf, ls, ztp);
        zt_reduce_kernel<8><<<dim3(1024), dim3(256), 0, stream>>>(ztp, ztb);
    } else if (ws_size >= base_b + (size_t)4 * ztf * 2) {
        zt_mfma_kernel<4><<<dim3(4, N_ / 128, B_), dim3(512), 0, stream>>>(xz, x, zf, ls, ztp);
        zt_reduce_kernel<4><<<dim3(1024), dim3(256), 0, stream>>>(ztp, ztb);
    } else {
        zt_mfma_kernel<2><<<dim3(2, N_ / 128, B_), dim3(512), 0, stream>>>(xz, x, zf, ls, ztp);
        zt_reduce_kernel<2><<<dim3(1024), dim3(256), 0, stream>>>(ztp, ztb);
    }

    // 136 upper-tri tile pairs x 16 (b,c) — TILE-FASTEST (R9's measured-best order)
    out_mfma_sym_kernel<<<dim3(136, B_ * C_), dim3(256), 0, stream>>>(ztb, out + M_);
}